// Round 5
// baseline (234.142 us; speedup 1.0000x reference)
//
#include <hip/hip_runtime.h>

// Sorting_84894323573304: out[b,i,:] = inputs[b, argsort(sum_c inputs*w)[b,i], :]
// B=32, N=131072, C=8, fp32.
//
// Key order (verified R3, absmax=0): sequential FMA chain (BLAS k-loop).
// Stable LSD radix (4 x 8-bit), payload = row idx.
// R5: pass-2 emits compressed u32 (key byte3 | idx17) -> final pass reads u32,
// LDS halves (22.5KB) -> 7 blocks/CU on the latency-bound fused scatter+gather.

#define NB   32
#define NPB  131072              // rows per batch (2^17)
#define NK   (NB * NPB)          // 4194304 keys total
#define TPB  256
#define EPT  16
#define EPB  (TPB * EPT)         // 4096 elems per block
#define BPB  (NPB / EPB)         // 32 blocks per batch
#define NBLK (NB * BPB)          // 1024
#define BINS 256

typedef unsigned long long u64;
typedef unsigned int u32;

__device__ __forceinline__ u32 fkey(float x) {
    u32 u = __float_as_uint(x);
    return u ^ ((u & 0x80000000u) ? 0xFFFFFFFFu : 0x80000000u);  // monotone fp32->u32
}

__device__ __forceinline__ u64 matchany(u32 d) {
    u64 m = ~0ull;
    #pragma unroll
    for (int k = 0; k < 8; ++k) {
        u64 bk = __ballot((d >> k) & 1u);
        m &= ((d >> k) & 1u) ? bk : ~bk;
    }
    return m;
}

// fused keygen + pass-0 (shift=32) histogram
__global__ void khist0(const float* __restrict__ in, const float* __restrict__ w,
                       u64* __restrict__ outp, u32* __restrict__ hist)
{
    __shared__ u32 h[BINS];
    int t = threadIdx.x;
    h[t] = 0;
    __syncthreads();
    int b = blockIdx.x / BPB, blk = blockIdx.x % BPB;
    size_t base = (size_t)b * NPB + (size_t)blk * EPB;
    int lane = t & 63;
    float w0 = w[0], w1 = w[1], w2 = w[2], w3 = w[3];
    float w4 = w[4], w5 = w[5], w6 = w[6], w7 = w[7];
    #pragma unroll
    for (int i = 0; i < EPT; ++i) {
        size_t row = base + t + i * TPB;
        const float4* p = (const float4*)in + row * 2;
        float4 a = p[0], c = p[1];
        // sequential accumulation, each op rounded once (matches np/BLAS k-loop)
        float k = __fmul_rn(a.x, w0);
        k = __fadd_rn(k, __fmul_rn(a.y, w1));
        k = __fadd_rn(k, __fmul_rn(a.z, w2));
        k = __fadd_rn(k, __fmul_rn(a.w, w3));
        k = __fadd_rn(k, __fmul_rn(c.x, w4));
        k = __fadd_rn(k, __fmul_rn(c.y, w5));
        k = __fadd_rn(k, __fmul_rn(c.z, w6));
        k = __fadd_rn(k, __fmul_rn(c.w, w7));
        u32 fk = fkey(k);
        outp[row] = ((u64)fk << 32) | (u64)((u32)row & (NPB - 1));
        u32 d = fk & 255u;
        u64 m = matchany(d);
        if (lane == __ffsll(m) - 1) atomicAdd(&h[d], (u32)__popcll(m));
    }
    __syncthreads();
    hist[(b * BINS + t) * BPB + blk] = h[t];
}

__global__ void rhist(const u64* __restrict__ src, u32* __restrict__ hist, int shift)
{
    __shared__ u32 h[BINS];
    int t = threadIdx.x;
    h[t] = 0;
    __syncthreads();
    int b = blockIdx.x / BPB, blk = blockIdx.x % BPB;
    size_t base = (size_t)b * NPB + (size_t)blk * EPB;
    int lane = t & 63;
    #pragma unroll
    for (int i = 0; i < EPT; ++i) {
        u64 v = src[base + t + i * TPB];
        u32 d = (u32)(v >> shift) & 255u;
        u64 m = matchany(d);
        if (lane == __ffsll(m) - 1) atomicAdd(&h[d], (u32)__popcll(m));
    }
    __syncthreads();
    hist[(b * BINS + t) * BPB + blk] = h[t];
}

// histogram over compressed u32 pairs (digit = bits 24-31)
__global__ void rhist32(const u32* __restrict__ src, u32* __restrict__ hist)
{
    __shared__ u32 h[BINS];
    int t = threadIdx.x;
    h[t] = 0;
    __syncthreads();
    int b = blockIdx.x / BPB, blk = blockIdx.x % BPB;
    size_t base = (size_t)b * NPB + (size_t)blk * EPB;
    int lane = t & 63;
    #pragma unroll
    for (int i = 0; i < EPT; ++i) {
        u32 v = src[base + t + i * TPB];
        u32 d = v >> 24;
        u64 m = matchany(d);
        if (lane == __ffsll(m) - 1) atomicAdd(&h[d], (u32)__popcll(m));
    }
    __syncthreads();
    hist[(b * BINS + t) * BPB + blk] = h[t];
}

// one block per batch: exclusive scan of 8192 entries (bin-major x block)
__global__ void rscan(u32* __restrict__ hist)
{
    int b = blockIdx.x, t = threadIdx.x;
    u32* H = hist + b * BINS * BPB;
    u32 v[32], s = 0;
    #pragma unroll
    for (int k = 0; k < 32; ++k) { v[k] = H[t * 32 + k]; s += v[k]; }
    int lane = t & 63, wid = t >> 6;
    u32 inc = s;
    #pragma unroll
    for (int off = 1; off < 64; off <<= 1) {
        u32 y = __shfl_up(inc, off, 64);
        if (lane >= off) inc += y;
    }
    __shared__ u32 wsum[4];
    if (lane == 63) wsum[wid] = inc;
    __syncthreads();
    u32 wo = 0;
    #pragma unroll
    for (int wI = 0; wI < 4; ++wI) if (wI < wid) wo += wsum[wI];
    u32 run = wo + inc - s;
    #pragma unroll
    for (int k = 0; k < 32; ++k) { u32 c = v[k]; H[t * 32 + k] = run; run += c; }
}

// shared ranking/permute body for u64 scatter passes.
#define RANK_PERMUTE_BODY(SRC_EXPR)                                             \
    int t = threadIdx.x, lane = t & 63, wid = t >> 6;                           \
    size_t base = (size_t)b * NPB + (size_t)blk * EPB + (size_t)wid * 1024;     \
    _Pragma("unroll")                                                           \
    for (int k = 0; k < 4; ++k) ((u32*)s_wcnt)[t + k * TPB] = 0;                \
    __syncthreads();                                                            \
    u64 v[EPT];                                                                 \
    u32 rnk[EPT];                                                               \
    _Pragma("unroll")                                                           \
    for (int i = 0; i < EPT; ++i) v[i] = (SRC_EXPR);                            \
    _Pragma("unroll")                                                           \
    for (int i = 0; i < EPT; ++i) {                                             \
        u32 d = (u32)(v[i] >> shift) & 255u;                                    \
        u64 m = matchany(d);                                                    \
        int leader = __ffsll(m) - 1;                                            \
        u32 baseCnt = 0;                                                        \
        if (lane == leader) {                                                   \
            baseCnt = s_wcnt[wid][d];                                           \
            s_wcnt[wid][d] = baseCnt + (u32)__popcll(m);                        \
        }                                                                       \
        baseCnt = __shfl(baseCnt, leader, 64);                                  \
        rnk[i] = baseCnt + (u32)__popcll(m & ((1ull << lane) - 1ull));          \
        __builtin_amdgcn_wave_barrier();                                        \
    }                                                                           \
    __syncthreads();                                                            \
    u32 c0 = s_wcnt[0][t], c1 = s_wcnt[1][t], c2 = s_wcnt[2][t], c3 = s_wcnt[3][t]; \
    u32 tot = c0 + c1 + c2 + c3;                                                \
    s_wcnt[0][t] = 0; s_wcnt[1][t] = c0; s_wcnt[2][t] = c0 + c1;                \
    s_wcnt[3][t] = c0 + c1 + c2;                                                \
    u32 inc = tot;                                                              \
    _Pragma("unroll")                                                           \
    for (int off = 1; off < 64; off <<= 1) {                                    \
        u32 y = __shfl_up(inc, off, 64);                                        \
        if (lane >= off) inc += y;                                              \
    }                                                                           \
    if (lane == 63) s_wsum[wid] = inc;                                          \
    __syncthreads();                                                            \
    u32 wo = 0;                                                                 \
    _Pragma("unroll")                                                           \
    for (int wI = 0; wI < 4; ++wI) if (wI < wid) wo += s_wsum[wI];              \
    s_dbase[t] = wo + inc - tot;                                                \
    s_gbase[t] = hist[(b * BINS + t) * BPB + blk];                              \
    __syncthreads();                                                            \
    _Pragma("unroll")                                                           \
    for (int i = 0; i < EPT; ++i) {                                             \
        u32 d = (u32)(v[i] >> shift) & 255u;                                    \
        u32 pos = s_dbase[d] + s_wcnt[wid][d] + rnk[i];                         \
        s_key[pos] = (u32)(v[i] >> 32);                                         \
        s_idx[pos] = (u32)v[i];                                                 \
    }                                                                           \
    __syncthreads();

__launch_bounds__(TPB, 4)
__global__ void rscatter(const u64* __restrict__ src, u64* __restrict__ dst,
                         const u32* __restrict__ hist, int shift)
{
    __shared__ u32 s_key[EPB];
    __shared__ u32 s_idx[EPB];
    __shared__ u32 s_wcnt[4][BINS];
    __shared__ u32 s_dbase[BINS];
    __shared__ u32 s_gbase[BINS];
    __shared__ u32 s_wsum[4];
    int b = blockIdx.x / BPB, blk = blockIdx.x % BPB;
    RANK_PERMUTE_BODY(src[base + i * 64 + lane])

    int kshift = shift - 32;
    #pragma unroll
    for (int i = 0; i < EPT; ++i) {
        int j = i * TPB + t;
        u32 key = s_key[j], idx = s_idx[j];
        u32 d = (key >> kshift) & 255u;
        u32 gpos = s_gbase[d] + (u32)j - s_dbase[d];
        dst[(size_t)b * NPB + gpos] = ((u64)key << 32) | (u64)idx;
    }
}

// pass-2 scatter: ranks on key bits 16-23, emits compressed u32 (byte3 | idx17)
__launch_bounds__(TPB, 4)
__global__ void rscat2c(const u64* __restrict__ src, u32* __restrict__ dstc,
                        const u32* __restrict__ hist)
{
    __shared__ u32 s_key[EPB];
    __shared__ u32 s_idx[EPB];
    __shared__ u32 s_wcnt[4][BINS];
    __shared__ u32 s_dbase[BINS];
    __shared__ u32 s_gbase[BINS];
    __shared__ u32 s_wsum[4];
    const int shift = 48;
    int b = blockIdx.x / BPB, blk = blockIdx.x % BPB;
    RANK_PERMUTE_BODY(src[base + i * 64 + lane])

    #pragma unroll
    for (int i = 0; i < EPT; ++i) {
        int j = i * TPB + t;
        u32 key = s_key[j], idx = s_idx[j];
        u32 d = (key >> 16) & 255u;
        u32 gpos = s_gbase[d] + (u32)j - s_dbase[d];
        dstc[(size_t)b * NPB + gpos] = (key & 0xFF000000u) | idx;  // byte3 | idx17
    }
}

// final MSB pass over compressed u32 pairs, fused with the row gather.
// LDS ~22.5KB -> 7 blocks/CU: concurrency for the latency-bound random reads.
__launch_bounds__(TPB, 6)
__global__ void rscatgat32(const u32* __restrict__ src, const float* __restrict__ in,
                           float* __restrict__ out, const u32* __restrict__ hist)
{
    __shared__ u32 s_pack[EPB];
    __shared__ u32 s_wcnt[4][BINS];
    __shared__ u32 s_dbase[BINS];
    __shared__ u32 s_gbase[BINS];
    __shared__ u32 s_wsum[4];
    // XCD batch-affinity swizzle (harmless; helps L2 batch locality)
    int i0 = blockIdx.x;
    int xcd = i0 & 7, j0 = i0 >> 3;
    int b = xcd + 8 * (j0 >> 5), blk = j0 & 31;

    int t = threadIdx.x, lane = t & 63, wid = t >> 6;
    size_t base = (size_t)b * NPB + (size_t)blk * EPB + (size_t)wid * 1024;
    #pragma unroll
    for (int k = 0; k < 4; ++k) ((u32*)s_wcnt)[t + k * TPB] = 0;
    __syncthreads();

    u32 v[EPT];
    u32 rnk[EPT];
    #pragma unroll
    for (int i = 0; i < EPT; ++i) v[i] = src[base + i * 64 + lane];

    #pragma unroll
    for (int i = 0; i < EPT; ++i) {
        u32 d = v[i] >> 24;
        u64 m = matchany(d);
        int leader = __ffsll(m) - 1;
        u32 baseCnt = 0;
        if (lane == leader) {
            baseCnt = s_wcnt[wid][d];
            s_wcnt[wid][d] = baseCnt + (u32)__popcll(m);
        }
        baseCnt = __shfl(baseCnt, leader, 64);
        rnk[i] = baseCnt + (u32)__popcll(m & ((1ull << lane) - 1ull));
        __builtin_amdgcn_wave_barrier();
    }
    __syncthreads();

    u32 c0 = s_wcnt[0][t], c1 = s_wcnt[1][t], c2 = s_wcnt[2][t], c3 = s_wcnt[3][t];
    u32 tot = c0 + c1 + c2 + c3;
    s_wcnt[0][t] = 0; s_wcnt[1][t] = c0; s_wcnt[2][t] = c0 + c1; s_wcnt[3][t] = c0 + c1 + c2;
    u32 inc = tot;
    #pragma unroll
    for (int off = 1; off < 64; off <<= 1) {
        u32 y = __shfl_up(inc, off, 64);
        if (lane >= off) inc += y;
    }
    if (lane == 63) s_wsum[wid] = inc;
    __syncthreads();
    u32 wo = 0;
    #pragma unroll
    for (int wI = 0; wI < 4; ++wI) if (wI < wid) wo += s_wsum[wI];
    s_dbase[t] = wo + inc - tot;
    s_gbase[t] = hist[(b * BINS + t) * BPB + blk];
    __syncthreads();

    #pragma unroll
    for (int i = 0; i < EPT; ++i) {
        u32 d = v[i] >> 24;
        u32 pos = s_dbase[d] + s_wcnt[wid][d] + rnk[i];
        s_pack[pos] = v[i];
    }
    __syncthreads();

    const float4* inb = (const float4*)in + ((size_t)b << 18); // b*NPB*2 float4s
    float4* outb = (float4*)out + ((size_t)b << 18);
    #pragma unroll
    for (int i = 0; i < EPT; ++i) {
        int j = i * TPB + t;
        u32 pack = s_pack[j];
        u32 d = pack >> 24;
        u32 idx = pack & 0x1FFFFu;
        u32 gpos = s_gbase[d] + (u32)j - s_dbase[d];
        const float4* s = inb + (size_t)idx * 2;
        float4 x = s[0], y = s[1];
        float4* drow = outb + (size_t)gpos * 2;
        drow[0] = x; drow[1] = y;
    }
}

extern "C" void kernel_launch(void* const* d_in, const int* in_sizes, int n_in,
                              void* d_out, int out_size, void* d_ws, size_t ws_size,
                              hipStream_t stream)
{
    const float* in = (const float*)d_in[0];
    const float* w  = (const float*)d_in[1];
    float* out = (float*)d_out;

    // ws: A (NK u64 = 33.5MB; u32 view uses first 16.8MB) + hist (1MB).
    // B aliases d_out (134MB, fully rewritten by rscatgat32 -> deterministic).
    u64* A   = (u64*)d_ws;
    u32* A32 = (u32*)d_ws;
    u64* B   = (u64*)d_out;
    u32* hist = (u32*)((char*)d_ws + (size_t)NK * 8);

    khist0<<<NBLK, TPB, 0, stream>>>(in, w, B, hist);
    rscan<<<NB, TPB, 0, stream>>>(hist);
    rscatter<<<NBLK, TPB, 0, stream>>>(B, A, hist, 32);

    rhist<<<NBLK, TPB, 0, stream>>>(A, hist, 40);
    rscan<<<NB, TPB, 0, stream>>>(hist);
    rscatter<<<NBLK, TPB, 0, stream>>>(A, B, hist, 40);

    rhist<<<NBLK, TPB, 0, stream>>>(B, hist, 48);
    rscan<<<NB, TPB, 0, stream>>>(hist);
    rscat2c<<<NBLK, TPB, 0, stream>>>(B, A32, hist);

    rhist32<<<NBLK, TPB, 0, stream>>>(A32, hist);
    rscan<<<NB, TPB, 0, stream>>>(hist);
    rscatgat32<<<NBLK, TPB, 0, stream>>>(A32, in, out, hist);
}